// Round 1
// baseline (1034.357 us; speedup 1.0000x reference)
//
#include <hip/hip_runtime.h>
#include <stdint.h>

// ---------------------------------------------------------------------------
// RCNN post-process: refine bboxes, sort by score, greedy NMS (IoU >= 0.2),
// output = [refined boxes (N*4 floats)] ++ [keep mask as 0/1 floats (N)]
// ---------------------------------------------------------------------------

#define THR        0.2f
#define THR_MARGIN 4e-6f

// ---------------- Kernel A: refine boxes (+ init pad boxes) ----------------
__global__ void k_refine(const float4* __restrict__ boxes,
                         const float4* __restrict__ deltas,
                         float4* __restrict__ out,        // d_out[0..4n)
                         float4* __restrict__ refined,    // ws
                         float4* __restrict__ sboxes,     // ws (pad init only)
                         int n, int npad) {
    int i = blockIdx.x * 256 + threadIdx.x;
    if (i >= n && i < npad) {
        // pad column boxes: far away, tiny, never intersect real boxes
        sboxes[i] = make_float4(-4.0e6f, -4.0e6f, -3.999999e6f, -3.999999e6f);
    }
    if (i >= n) return;
    float4 b = boxes[i];
    float4 d = deltas[i];
    // exact op order of the reference, no FMA contraction
    float x = __fmul_rn(__fadd_rn(b.x, b.z), 0.5f);
    float y = __fmul_rn(__fadd_rn(b.y, b.w), 0.5f);
    float w = __fsub_rn(b.z, b.x);
    float h = __fsub_rn(b.w, b.y);
    float nx = __fadd_rn(x, __fmul_rn(w, d.x));
    float ny = __fadd_rn(y, __fmul_rn(h, d.y));
    float ew = (float)exp((double)d.z);   // correctly-rounded f32 exp
    float eh = (float)exp((double)d.w);
    float nw = __fmul_rn(w, ew);
    float nh = __fmul_rn(h, eh);
    float hx = __fmul_rn(nw, 0.5f);
    float hy = __fmul_rn(nh, 0.5f);
    float4 o = make_float4(__fsub_rn(nx, hx), __fsub_rn(ny, hy),
                           __fadd_rn(nx, hx), __fadd_rn(ny, hy));
    refined[i] = o;
    out[i]     = o;
}

// ---------------- Kernel B: stable-descending rank + scatter ----------------
// 4 threads per box i; scores staged in LDS.
__global__ void k_rank(const float* __restrict__ scores,
                       const float4* __restrict__ refined,
                       float4* __restrict__ sboxes,
                       int* __restrict__ origIdx,
                       int n) {
    __shared__ __align__(16) float s[10016];
    int t = threadIdx.x;
    for (int idx = t; idx < n; idx += 256) s[idx] = scores[idx];
    __syncthreads();

    int i = blockIdx.x * 64 + (t >> 2);
    if (i >= n) return;
    int q = t & 3;
    float si = s[i];
    int j0 = (n * q) >> 2;
    int j1 = (n * (q + 1)) >> 2;
    int cnt = 0;

    int ja = (j0 + 3) & ~3;
    int jb = j1 & ~3;
    for (int j = j0; j < ja && j < j1; ++j) {
        float sj = s[j];
        cnt += (sj > si) || (sj == si && j < i);
    }
    const float4* sv = (const float4*)s;
    for (int j4 = ja >> 2; j4 < (jb >> 2); ++j4) {
        float4 v = sv[j4];
        int j = j4 << 2;
        cnt += (v.x > si) || (v.x == si && (j + 0) < i);
        cnt += (v.y > si) || (v.y == si && (j + 1) < i);
        cnt += (v.z > si) || (v.z == si && (j + 2) < i);
        cnt += (v.w > si) || (v.w == si && (j + 3) < i);
    }
    for (int j = jb > j0 ? jb : j0; j < j1; ++j) {
        float sj = s[j];
        cnt += (sj > si) || (sj == si && j < i);
    }
    // combine the 4 partials (lanes t^1, t^2 within same wave)
    cnt += __shfl_xor(cnt, 1, 64);
    cnt += __shfl_xor(cnt, 2, 64);
    if (q == 0) {
        sboxes[cnt]  = refined[i];
        origIdx[cnt] = i;
    }
}

// ---------------- Kernel C: suppression bitmask (upper triangle) ------------
// Block: 16 rows x 16 words (64 cols/word). Columns LDS-tiled 1024 at a time.
#define C_ROWS 16
#define C_TILE 1024
__global__ void k_mask(const float4* __restrict__ sboxes,
                       unsigned long long* __restrict__ mask,
                       int n, int npad, int words, int stride) {
    __shared__ __align__(16) float4 tileb[C_TILE];
    int t  = threadIdx.x;
    int rl = t >> 4;   // 0..15 row within block
    int wl = t & 15;   // 0..15 word within tile
    int r  = blockIdx.x * C_ROWS + rl;
    bool rvalid = (r < n);
    float4 rb = rvalid ? sboxes[r] : make_float4(0.f, 0.f, 1.f, 1.f);
    float ra = __fmul_rn(__fsub_rn(rb.z, rb.x), __fsub_rn(rb.w, rb.y));

    int ntiles = (npad + C_TILE - 1) / C_TILE;
    for (int tile = 0; tile < ntiles; ++tile) {
        int c0t = tile * C_TILE;
        __syncthreads();
        for (int idx = t; idx < C_TILE; idx += 256) {
            int c = c0t + idx;
            tileb[idx] = (c < npad) ? sboxes[c]
                                    : make_float4(-4.0e6f, -4.0e6f,
                                                  -3.999999e6f, -3.999999e6f);
        }
        __syncthreads();

        int w     = (c0t >> 6) + wl;     // global word index
        int cbase = c0t + (wl << 6);
        unsigned long long bits = 0ULL;
        bool active = rvalid && (w < words) && (cbase + 63 > r);
        if (active) {
            for (int sidx = 0; sidx < 64; ++sidx) {
                int sw = (sidx + wl) & 63;          // bank-conflict swizzle
                int c  = cbase + sw;
                float4 cb = tileb[(wl << 6) + sw];
                float xl = fmaxf(rb.x, cb.x);
                float yt = fmaxf(rb.y, cb.y);
                float xr = fminf(rb.z, cb.z);
                float yb = fminf(rb.w, cb.w);
                float iw = fmaxf(__fsub_rn(xr, xl), 0.0f);
                float ih = fmaxf(__fsub_rn(yb, yt), 0.0f);
                float inter = __fmul_rn(iw, ih);
                bool sup = false;
                if (inter > 0.0f && c > r) {
                    float ca  = __fmul_rn(__fsub_rn(cb.z, cb.x),
                                          __fsub_rn(cb.w, cb.y));
                    float uni = __fsub_rn(__fadd_rn(ra, ca), inter);
                    float approx = __fmul_rn(inter, __builtin_amdgcn_rcpf(uni));
                    float diff = approx - THR;
                    if (diff > THR_MARGIN)       sup = true;
                    else if (diff < -THR_MARGIN) sup = false;
                    else                         sup = ((inter / uni) >= THR); // IEEE div
                }
                bits |= ((unsigned long long)sup) << sw;
            }
        }
        if (rvalid && w < words) mask[(size_t)r * stride + w] = bits;
    }
}

// ---------------- Kernel D: sequential greedy scan (1 wave) -----------------
// removed mask in registers: lane l owns words l, 64+l, 128+l.
__global__ void k_scan(const unsigned long long* __restrict__ mask,
                       const int* __restrict__ origIdx,
                       float* __restrict__ keep_out,
                       int n, int words, int stride) {
    int l = threadIdx.x;  // 0..63
    unsigned long long rem0 = 0, rem1 = 0, rem2 = 0;
    for (int g = 0; g < words; ++g) {
        int k = g >> 6, owner = g & 63;
        unsigned long long myw = (k == 0) ? rem0 : ((k == 1) ? rem1 : rem2);
        unsigned long long W =
            (unsigned long long)__shfl((long long)myw, owner, 64);
        int rbase = g << 6;
        int bmax = n - rbase; if (bmax > 64) bmax = 64;
        for (int b = 0; b < bmax; ++b) {
            if (!((W >> b) & 1ULL)) {   // row kept -> OR its suppression row
                const unsigned long long* row = mask + (size_t)(rbase + b) * stride;
                unsigned long long v0 = row[l];
                unsigned long long v1 = (64 + l < words) ? row[64 + l] : 0ULL;
                unsigned long long v2 = (128 + l < words) ? row[128 + l] : 0ULL;
                rem0 |= v0; rem1 |= v1; rem2 |= v2;
                unsigned long long vk = (k == 0) ? v0 : ((k == 1) ? v1 : v2);
                W |= (unsigned long long)__shfl((long long)vk, owner, 64);
            }
        }
    }
    __shared__ unsigned long long rs[192];
    rs[l] = rem0; rs[64 + l] = rem1; rs[128 + l] = rem2;
    __syncthreads();
    for (int r = l; r < n; r += 64) {
        unsigned long long wv = rs[r >> 6];
        int bit = (int)((wv >> (r & 63)) & 1ULL);
        keep_out[origIdx[r]] = bit ? 0.0f : 1.0f;
    }
}

// ---------------------------------------------------------------------------
extern "C" void kernel_launch(void* const* d_in, const int* in_sizes, int n_in,
                              void* d_out, int out_size, void* d_ws, size_t ws_size,
                              hipStream_t stream) {
    const float4* boxes  = (const float4*)d_in[0];
    const float4* deltas = (const float4*)d_in[1];
    const float*  scores = (const float*)d_in[2];
    int n = in_sizes[2];                        // 10000
    int words  = (n + 63) >> 6;                 // 157
    int stride = (words + 3) & ~3;              // 160 (u64 words per row)
    int npad   = ((n + C_TILE - 1) / C_TILE) * C_TILE;  // 10240

    char* ws = (char*)d_ws;
    float4* refined = (float4*)ws;                                  // npad*16
    float4* sboxes  = (float4*)(ws + (size_t)npad * 16);            // npad*16
    int*    origIdx = (int*)(ws + (size_t)npad * 32);               // n*4
    size_t  moff    = ((size_t)npad * 32 + (size_t)n * 4 + 1023) & ~(size_t)1023;
    unsigned long long* mask = (unsigned long long*)(ws + moff);    // n*stride*8

    float* out = (float*)d_out;

    k_refine<<<(npad + 255) / 256, 256, 0, stream>>>(
        boxes, deltas, (float4*)out, refined, sboxes, n, npad);
    k_rank<<<(n + 63) / 64, 256, 0, stream>>>(scores, refined, sboxes, origIdx, n);
    k_mask<<<(n + C_ROWS - 1) / C_ROWS, 256, 0, stream>>>(
        sboxes, mask, n, npad, words, stride);
    k_scan<<<1, 64, 0, stream>>>(mask, origIdx, out + (size_t)n * 4, n, words, stride);
}

// Round 2
// 546.372 us; speedup vs baseline: 1.8931x; 1.8931x over previous
//
#include <hip/hip_runtime.h>
#include <stdint.h>

// ---------------------------------------------------------------------------
// RCNN post-process: refine bboxes, sort by score, greedy NMS (IoU >= 0.2),
// output = [refined boxes (N*4 floats)] ++ [keep mask as 0/1 floats (N)]
// ---------------------------------------------------------------------------

#define THR        0.2f
#define THR_MARGIN 4e-6f

typedef unsigned long long u64;
typedef unsigned int       u32;

// ---------------- Kernel A: refine boxes (+ init pad boxes) ----------------
__global__ void k_refine(const float4* __restrict__ boxes,
                         const float4* __restrict__ deltas,
                         float4* __restrict__ out,        // d_out[0..4n)
                         float4* __restrict__ refined,    // ws
                         float4* __restrict__ sboxes,     // ws (pad init only)
                         int n, int npad) {
    int i = blockIdx.x * 256 + threadIdx.x;
    if (i >= n && i < npad) {
        // pad column boxes: far away, tiny, never intersect real boxes
        sboxes[i] = make_float4(-4.0e6f, -4.0e6f, -3.999999e6f, -3.999999e6f);
    }
    if (i >= n) return;
    float4 b = boxes[i];
    float4 d = deltas[i];
    // exact op order of the reference, no FMA contraction
    float x = __fmul_rn(__fadd_rn(b.x, b.z), 0.5f);
    float y = __fmul_rn(__fadd_rn(b.y, b.w), 0.5f);
    float w = __fsub_rn(b.z, b.x);
    float h = __fsub_rn(b.w, b.y);
    float nx = __fadd_rn(x, __fmul_rn(w, d.x));
    float ny = __fadd_rn(y, __fmul_rn(h, d.y));
    float ew = (float)exp((double)d.z);   // correctly-rounded f32 exp
    float eh = (float)exp((double)d.w);
    float nw = __fmul_rn(w, ew);
    float nh = __fmul_rn(h, eh);
    float hx = __fmul_rn(nw, 0.5f);
    float hy = __fmul_rn(nh, 0.5f);
    float4 o = make_float4(__fsub_rn(nx, hx), __fsub_rn(ny, hy),
                           __fadd_rn(nx, hx), __fadd_rn(ny, hy));
    refined[i] = o;
    out[i]     = o;
}

// ---------------- Kernel B: stable-descending rank + scatter ----------------
// 4 threads per box i; scores staged in LDS.
__global__ void k_rank(const float* __restrict__ scores,
                       const float4* __restrict__ refined,
                       float4* __restrict__ sboxes,
                       int* __restrict__ origIdx,
                       int n) {
    __shared__ __align__(16) float s[10016];
    int t = threadIdx.x;
    for (int idx = t; idx < n; idx += 256) s[idx] = scores[idx];
    __syncthreads();

    int i = blockIdx.x * 64 + (t >> 2);
    if (i >= n) return;
    int q = t & 3;
    float si = s[i];
    int j0 = (n * q) >> 2;
    int j1 = (n * (q + 1)) >> 2;
    int cnt = 0;

    int ja = (j0 + 3) & ~3;
    int jb = j1 & ~3;
    for (int j = j0; j < ja && j < j1; ++j) {
        float sj = s[j];
        cnt += (sj > si) || (sj == si && j < i);
    }
    const float4* sv = (const float4*)s;
    for (int j4 = ja >> 2; j4 < (jb >> 2); ++j4) {
        float4 v = sv[j4];
        int j = j4 << 2;
        cnt += (v.x > si) || (v.x == si && (j + 0) < i);
        cnt += (v.y > si) || (v.y == si && (j + 1) < i);
        cnt += (v.z > si) || (v.z == si && (j + 2) < i);
        cnt += (v.w > si) || (v.w == si && (j + 3) < i);
    }
    for (int j = jb > j0 ? jb : j0; j < j1; ++j) {
        float sj = s[j];
        cnt += (sj > si) || (sj == si && j < i);
    }
    // combine the 4 partials (lanes t^1, t^2 within same wave)
    cnt += __shfl_xor(cnt, 1, 64);
    cnt += __shfl_xor(cnt, 2, 64);
    if (q == 0) {
        sboxes[cnt]  = refined[i];
        origIdx[cnt] = i;
    }
}

// ---------------- Kernel C: suppression bitmask (upper triangle) ------------
// Block: 16 rows x 16 words (64 cols/word). Columns LDS-tiled 1024 at a time.
// Starts at the diagonal tile; fully-sub-diagonal mask words are left
// unwritten (k_scan only ever consumes rem[w] at group w, and pollution from
// a kept row r arrives at group (r>>6) > w, so garbage there is never read
// before it is dead).
#define C_ROWS 16
#define C_TILE 1024
__global__ void k_mask(const float4* __restrict__ sboxes,
                       u64* __restrict__ mask,
                       int n, int npad, int words, int stride) {
    __shared__ __align__(16) float4 tileb[C_TILE];
    int t  = threadIdx.x;
    int rl = t >> 4;   // 0..15 row within block
    int wl = t & 15;   // 0..15 word within tile
    int r0 = blockIdx.x * C_ROWS;
    int r  = r0 + rl;
    bool rvalid = (r < n);
    float4 rb = rvalid ? sboxes[r] : make_float4(0.f, 0.f, 1.f, 1.f);
    float ra = __fmul_rn(__fsub_rn(rb.z, rb.x), __fsub_rn(rb.w, rb.y));

    int ntiles = (npad + C_TILE - 1) / C_TILE;
    int tile0  = r0 >> 10;   // first tile containing any column > r0
    for (int tile = tile0; tile < ntiles; ++tile) {
        int c0t = tile * C_TILE;
        __syncthreads();
        for (int idx = t; idx < C_TILE; idx += 256) {
            int c = c0t + idx;
            tileb[idx] = (c < npad) ? sboxes[c]
                                    : make_float4(-4.0e6f, -4.0e6f,
                                                  -3.999999e6f, -3.999999e6f);
        }
        __syncthreads();

        int w     = (c0t >> 6) + wl;     // global word index
        int cbase = c0t + (wl << 6);
        u64 bits = 0ULL;
        bool active = rvalid && (w < words) && (cbase + 63 > r);
        if (active) {
            for (int sidx = 0; sidx < 64; ++sidx) {
                int sw = (sidx + wl) & 63;          // bank-conflict swizzle
                int c  = cbase + sw;
                float4 cb = tileb[(wl << 6) + sw];
                float xl = fmaxf(rb.x, cb.x);
                float yt = fmaxf(rb.y, cb.y);
                float xr = fminf(rb.z, cb.z);
                float yb = fminf(rb.w, cb.w);
                float iw = fmaxf(__fsub_rn(xr, xl), 0.0f);
                float ih = fmaxf(__fsub_rn(yb, yt), 0.0f);
                float inter = __fmul_rn(iw, ih);
                bool sup = false;
                if (inter > 0.0f && c > r) {
                    float ca  = __fmul_rn(__fsub_rn(cb.z, cb.x),
                                          __fsub_rn(cb.w, cb.y));
                    float uni = __fsub_rn(__fadd_rn(ra, ca), inter);
                    float approx = __fmul_rn(inter, __builtin_amdgcn_rcpf(uni));
                    float diff = approx - THR;
                    if (diff > THR_MARGIN)       sup = true;
                    else if (diff < -THR_MARGIN) sup = false;
                    else                         sup = ((inter / uni) >= THR); // IEEE div
                }
                bits |= ((u64)sup) << sw;
            }
        }
        if (rvalid && w < words) mask[(size_t)r * stride + w] = bits;
    }
}

// ---------------- Kernel D: grouped greedy scan (1 wave) --------------------
// 157 groups of 64 rows. Per group: prefetched diagonal word block D in
// registers, ff1-driven in-register scan via v_readlane, then batched
// full-row ORs of kept rows into the distributed rem registers
// (lane l owns words l, 64+l, 128+l).
__global__ void k_scan(const u64* __restrict__ mask,
                       const int* __restrict__ origIdx,
                       float* __restrict__ keep_out,
                       int n, int words, int stride) {
    int l = threadIdx.x;  // 0..63
    u64 rem0 = 0, rem1 = 0, rem2 = 0;
    __shared__ u64 ks[192];

    // prefetch diagonal block for group 0
    u64 D = 0;
    if (l < n) D = mask[(size_t)l * stride + 0];
    u64 W = 0;   // suppression word for current group (uniform)

    for (int g = 0; g < words; ++g) {
        int rbase = g << 6;
        int nv = n - rbase; if (nv > 64) nv = 64;
        u64 validmask = (nv >= 64) ? ~0ULL : ((1ULL << nv) - 1ULL);

        // prefetch next group's diagonal block (independent of rem)
        u64 Dn = 0;
        int rn = rbase + 64 + l;
        if (g + 1 < words && rn < n)
            Dn = mask[(size_t)rn * stride + (g + 1)];

        // ---- in-register scan over alive candidates (ascending order) ----
        u64 Wl = W | ~validmask;
        u32 dlo = (u32)D, dhi = (u32)(D >> 32);
        u64 cand = ~Wl;           // candidate rows not yet processed/suppressed
        while (cand) {
            int b = __builtin_ctzll(cand);           // uniform
            u64 Db = ((u64)__builtin_amdgcn_readlane(dhi, (u32)b) << 32)
                   |  (u64)__builtin_amdgcn_readlane(dlo, (u32)b);
            Wl   |= Db;                              // Db bits are all > b
            cand &= ~(Db | (1ULL << b));
        }
        u64 K = validmask & ~Wl;   // kept rows of this group (uniform)
        if (l == 0) ks[g] = K;

        // ---- batched full-row OR of kept rows into rem ----
        u64 kk = K;
        while (kk) {
            int b0 = (int)__builtin_ctzll(kk); kk &= kk - 1;
            int b1 = -1, b2 = -1, b3 = -1;
            if (kk) { b1 = (int)__builtin_ctzll(kk); kk &= kk - 1; }
            if (kk) { b2 = (int)__builtin_ctzll(kk); kk &= kk - 1; }
            if (kk) { b3 = (int)__builtin_ctzll(kk); kk &= kk - 1; }
            const u64* p0 = mask + (size_t)(rbase + b0) * stride;
            u64 a0 = p0[l];
            u64 a1 = p0[64 + l];
            u64 a2 = (128 + l < words) ? p0[128 + l] : 0ULL;
            u64 c0 = 0, c1 = 0, c2 = 0, d0 = 0, d1 = 0, d2 = 0;
            u64 e0 = 0, e1 = 0, e2 = 0;
            if (b1 >= 0) {
                const u64* p = mask + (size_t)(rbase + b1) * stride;
                c0 = p[l]; c1 = p[64 + l];
                c2 = (128 + l < words) ? p[128 + l] : 0ULL;
            }
            if (b2 >= 0) {
                const u64* p = mask + (size_t)(rbase + b2) * stride;
                d0 = p[l]; d1 = p[64 + l];
                d2 = (128 + l < words) ? p[128 + l] : 0ULL;
            }
            if (b3 >= 0) {
                const u64* p = mask + (size_t)(rbase + b3) * stride;
                e0 = p[l]; e1 = p[64 + l];
                e2 = (128 + l < words) ? p[128 + l] : 0ULL;
            }
            rem0 |= a0 | c0 | d0 | e0;
            rem1 |= a1 | c1 | d1 | e1;
            rem2 |= a2 | c2 | d2 | e2;
        }

        // ---- seed next group's suppression word ----
        if (g + 1 < words) {
            int gn = g + 1, k = gn >> 6, owner = gn & 63;
            u64 myw = (k == 0) ? rem0 : ((k == 1) ? rem1 : rem2);
            u32 wlo = __builtin_amdgcn_readlane((u32)myw, (u32)owner);
            u32 whi = __builtin_amdgcn_readlane((u32)(myw >> 32), (u32)owner);
            W = ((u64)whi << 32) | wlo;
            D = Dn;
        }
    }
    __syncthreads();
    for (int r = l; r < n; r += 64) {
        int bit = (int)((ks[r >> 6] >> (r & 63)) & 1ULL);   // 1 = kept
        keep_out[origIdx[r]] = bit ? 1.0f : 0.0f;
    }
}

// ---------------------------------------------------------------------------
extern "C" void kernel_launch(void* const* d_in, const int* in_sizes, int n_in,
                              void* d_out, int out_size, void* d_ws, size_t ws_size,
                              hipStream_t stream) {
    const float4* boxes  = (const float4*)d_in[0];
    const float4* deltas = (const float4*)d_in[1];
    const float*  scores = (const float*)d_in[2];
    int n = in_sizes[2];                        // 10000
    int words  = (n + 63) >> 6;                 // 157
    int stride = (words + 3) & ~3;              // 160 (u64 words per row)
    int npad   = ((n + C_TILE - 1) / C_TILE) * C_TILE;  // 10240

    char* ws = (char*)d_ws;
    float4* refined = (float4*)ws;                                  // npad*16
    float4* sboxes  = (float4*)(ws + (size_t)npad * 16);            // npad*16
    int*    origIdx = (int*)(ws + (size_t)npad * 32);               // n*4
    size_t  moff    = ((size_t)npad * 32 + (size_t)n * 4 + 1023) & ~(size_t)1023;
    u64*    mask    = (u64*)(ws + moff);                            // n*stride*8

    float* out = (float*)d_out;

    k_refine<<<(npad + 255) / 256, 256, 0, stream>>>(
        boxes, deltas, (float4*)out, refined, sboxes, n, npad);
    k_rank<<<(n + 63) / 64, 256, 0, stream>>>(scores, refined, sboxes, origIdx, n);
    k_mask<<<(n + C_ROWS - 1) / C_ROWS, 256, 0, stream>>>(
        sboxes, mask, n, npad, words, stride);
    k_scan<<<1, 64, 0, stream>>>(mask, origIdx, out + (size_t)n * 4, n, words, stride);
}

// Round 3
// 455.273 us; speedup vs baseline: 2.2719x; 1.2001x over previous
//
#include <hip/hip_runtime.h>
#include <stdint.h>

// ---------------------------------------------------------------------------
// RCNN post-process: refine bboxes, sort by score, greedy NMS (IoU >= 0.2),
// output = [refined boxes (N*4 floats)] ++ [keep mask as 0/1 floats (N)]
// ---------------------------------------------------------------------------

#define THR        0.2f
#define BORDER_EPS 1e-6f

typedef unsigned long long u64;
typedef unsigned int       u32;

// ---------------- Kernel A: refine boxes (+ init pad boxes) ----------------
__global__ void k_refine(const float4* __restrict__ boxes,
                         const float4* __restrict__ deltas,
                         float4* __restrict__ out,        // d_out[0..4n)
                         float4* __restrict__ refined,    // ws
                         float4* __restrict__ sboxes,     // ws (pad init only)
                         int n, int npad) {
    int i = blockIdx.x * 256 + threadIdx.x;
    if (i >= n && i < npad) {
        sboxes[i] = make_float4(-4.0e6f, -4.0e6f, -3.999999e6f, -3.999999e6f);
    }
    if (i >= n) return;
    float4 b = boxes[i];
    float4 d = deltas[i];
    float x = __fmul_rn(__fadd_rn(b.x, b.z), 0.5f);
    float y = __fmul_rn(__fadd_rn(b.y, b.w), 0.5f);
    float w = __fsub_rn(b.z, b.x);
    float h = __fsub_rn(b.w, b.y);
    float nx = __fadd_rn(x, __fmul_rn(w, d.x));
    float ny = __fadd_rn(y, __fmul_rn(h, d.y));
    float ew = (float)exp((double)d.z);   // correctly-rounded f32 exp
    float eh = (float)exp((double)d.w);
    float nw = __fmul_rn(w, ew);
    float nh = __fmul_rn(h, eh);
    float hx = __fmul_rn(nw, 0.5f);
    float hy = __fmul_rn(nh, 0.5f);
    float4 o = make_float4(__fsub_rn(nx, hx), __fsub_rn(ny, hy),
                           __fadd_rn(nx, hx), __fadd_rn(ny, hy));
    refined[i] = o;
    out[i]     = o;
}

// ---------------- Kernel B: stable-descending rank + scatter ----------------
__global__ void k_rank(const float* __restrict__ scores,
                       const float4* __restrict__ refined,
                       float4* __restrict__ sboxes,
                       int* __restrict__ origIdx,
                       int n) {
    __shared__ __align__(16) float s[10016];
    int t = threadIdx.x;
    for (int idx = t; idx < n; idx += 256) s[idx] = scores[idx];
    __syncthreads();

    int i = blockIdx.x * 64 + (t >> 2);
    if (i >= n) return;
    int q = t & 3;
    float si = s[i];
    int j0 = (n * q) >> 2;
    int j1 = (n * (q + 1)) >> 2;
    int cnt = 0;

    int ja = (j0 + 3) & ~3;
    int jb = j1 & ~3;
    for (int j = j0; j < ja && j < j1; ++j) {
        float sj = s[j];
        cnt += (sj > si) || (sj == si && j < i);
    }
    const float4* sv = (const float4*)s;
    for (int j4 = ja >> 2; j4 < (jb >> 2); ++j4) {
        float4 v = sv[j4];
        int j = j4 << 2;
        cnt += (v.x > si) || (v.x == si && (j + 0) < i);
        cnt += (v.y > si) || (v.y == si && (j + 1) < i);
        cnt += (v.z > si) || (v.z == si && (j + 2) < i);
        cnt += (v.w > si) || (v.w == si && (j + 3) < i);
    }
    for (int j = jb > j0 ? jb : j0; j < j1; ++j) {
        float sj = s[j];
        cnt += (sj > si) || (sj == si && j < i);
    }
    cnt += __shfl_xor(cnt, 1, 64);
    cnt += __shfl_xor(cnt, 2, 64);
    if (q == 0) {
        sboxes[cnt]  = refined[i];
        origIdx[cnt] = i;
    }
}

// ---------------- Kernel C: suppression bitmask, column-per-thread ----------
// thread = one column (its box in registers); rows broadcast from LDS.
// Decision: t = fma(uni, -THR, inter); sign decides unless |t| <= eps*uni
// (then exact IEEE division fallback, matches numpy bit-for-bit).
// Word for (row r, this wave) produced by __ballot; bits c<=r masked off.
// Words fully below the diagonal are never written (k_scan never consumes
// them before they are dead).
#define M_COLS   256
#define M_RCHUNK 512
__global__ void k_mask(const float4* __restrict__ sboxes,
                       u64* __restrict__ mask,
                       int n, int npad, int words, int stride) {
    __shared__ __align__(16) float4 rowbox[M_RCHUNK];
    int tid = threadIdx.x;
    int c0  = blockIdx.x * M_COLS;
    int rc0 = blockIdx.y * M_RCHUNK;
    if (rc0 >= c0 + M_COLS || rc0 >= n) return;   // fully sub-diagonal / OOR

    int c = c0 + tid;
    float4 cbx = sboxes[c];
    float ca = __fmul_rn(__fsub_rn(cbx.z, cbx.x), __fsub_rn(cbx.w, cbx.y));
    int lane  = tid & 63;
    int wword = (c0 >> 6) + (tid >> 6);
    int cbase = wword << 6;

    int rlim_chunk = rc0 + M_RCHUNK; if (rlim_chunk > n) rlim_chunk = n;
    for (int j = tid; j < rlim_chunk - rc0; j += 256)
        rowbox[j] = sboxes[rc0 + j];
    __syncthreads();

    int rlim = rlim_chunk; if (rlim > cbase + 64) rlim = cbase + 64;
    for (int r = rc0; r < rlim; ++r) {
        float4 rb = rowbox[r - rc0];                       // uniform broadcast
        float ra = __fmul_rn(__fsub_rn(rb.z, rb.x), __fsub_rn(rb.w, rb.y));
        float xl = fmaxf(rb.x, cbx.x);
        float yt = fmaxf(rb.y, cbx.y);
        float xr = fminf(rb.z, cbx.z);
        float yb = fminf(rb.w, cbx.w);
        float iw = fmaxf(__fsub_rn(xr, xl), 0.0f);
        float ih = fmaxf(__fsub_rn(yb, yt), 0.0f);
        float inter = __fmul_rn(iw, ih);
        float uni = __fsub_rn(__fadd_rn(ra, ca), inter);
        float t = fmaf(uni, -THR, inter);                  // single-rounded
        bool sup = (t >= 0.0f);
        bool border = (fabsf(t) <= __fmul_rn(BORDER_EPS, uni));
        if (__any(border)) {                               // rare
            float q = inter / uni;                         // IEEE f32 div
            bool s2 = (q >= THR);
            sup = border ? s2 : sup;
        }
        u64 wvals = __ballot(sup);
        if (lane == 0) {
            u64 rmask = ~0ULL;
            if (r >= cbase) {
                int s = r - cbase;                         // 0..63
                rmask = (s >= 63) ? 0ULL : (~0ULL << (s + 1));
            }
            mask[(size_t)r * stride + wword] = wvals & rmask;
        }
    }
}

// ---------------- Kernel D: grouped greedy scan, 4-wave role-split ----------
// wave 0: serial in-register scan per group (D column prefetched) + E-column
//         masked butterfly-OR to seed next group's W without memory latency.
// waves 1-3: thread 64+i owns mask word i; full-row ORs of kept rows lag one
//         group, overlapping their load latency with wave 0's scan.
__global__ void k_scan(const u64* __restrict__ mask,
                       const int* __restrict__ origIdx,
                       float* __restrict__ keep_out,
                       int n, int words, int stride) {
    __shared__ u64 ks[160];
    __shared__ u64 wslot;
    int tid   = threadIdx.x;
    int lane  = tid & 63;
    int wv    = tid >> 6;
    int owner = tid - 64;            // word owned by waves 1-3
    u64 rem = 0;

    u64 W = 0, D = 0, E = 0, Ered = 0;
    if (wv == 0 && lane < n) {
        D = mask[(size_t)lane * stride + 0];
        E = mask[(size_t)lane * stride + 1];
    }

    for (int g = 0; g < words; ++g) {
        int rbase = g << 6;
        if (wv == 0) {
            // ---- prefetch next group's D/E (consumed next iteration) ----
            u64 Dn = 0, En = 0;
            int rn = rbase + 64 + lane;
            if (g + 1 < words && rn < n) {
                const u64* p = mask + (size_t)rn * stride;
                Dn = p[g + 1];
                En = p[g + 2];       // g+2 <= 158 < stride(160): in-bounds
            }
            // ---- serial in-register scan of this group ----
            int nv = n - rbase; if (nv > 64) nv = 64;
            u64 validmask = (nv >= 64) ? ~0ULL : ((1ULL << nv) - 1ULL);
            u64 Wl = W | ~validmask;
            u32 dlo = (u32)D, dhi = (u32)(D >> 32);
            u64 cand = ~Wl;
            while (cand) {
                int b = __builtin_ctzll(cand);
                u64 Db = ((u64)__builtin_amdgcn_readlane(dhi, (u32)b) << 32)
                       |  (u64)__builtin_amdgcn_readlane(dlo, (u32)b);
                Wl   |= Db;
                cand &= ~(Db | (1ULL << b));
            }
            u64 K = validmask & ~Wl;
            if (lane == 0) ks[g] = K;
            // ---- Ered = OR of E over kept lanes (butterfly) ----
            u64 take = ((K >> lane) & 1ULL) ? E : 0ULL;
            #pragma unroll
            for (int s = 1; s < 64; s <<= 1)
                take |= (u64)__shfl_xor((long long)take, s, 64);
            Ered = take;
            D = Dn; E = En;
        } else if (owner >= 0 && owner < words && g > 0) {
            // ---- lagged full-row OR of kept(g-1) ----
            u64 kk = ks[g - 1];
            const u64* bp = mask + (size_t)((g - 1) << 6) * stride + owner;
            while (kk) {
                u64 v0=0,v1=0,v2=0,v3=0,v4=0,v5=0,v6=0,v7=0;
                u64 v8=0,v9=0,v10=0,v11=0,v12=0,v13=0,v14=0,v15=0;
                int b;
#define KLOAD(vi) if (kk) { b = __builtin_ctzll(kk); kk &= kk - 1; \
                            vi = bp[(size_t)b * stride]; }
                KLOAD(v0)  KLOAD(v1)  KLOAD(v2)  KLOAD(v3)
                KLOAD(v4)  KLOAD(v5)  KLOAD(v6)  KLOAD(v7)
                KLOAD(v8)  KLOAD(v9)  KLOAD(v10) KLOAD(v11)
                KLOAD(v12) KLOAD(v13) KLOAD(v14) KLOAD(v15)
#undef KLOAD
                rem |= ((v0|v1)|(v2|v3)) | ((v4|v5)|(v6|v7))
                     | ((v8|v9)|(v10|v11)) | ((v12|v13)|(v14|v15));
            }
        }
        __syncthreads();
        if (g + 1 < words && tid == 64 + (g + 1)) wslot = rem;
        __syncthreads();
        if (wv == 0 && g + 1 < words) W = wslot | Ered;
    }

    __syncthreads();
    for (int r = tid; r < n; r += 256) {
        int bit = (int)((ks[r >> 6] >> (r & 63)) & 1ULL);   // 1 = kept
        keep_out[origIdx[r]] = bit ? 1.0f : 0.0f;
    }
}

// ---------------------------------------------------------------------------
extern "C" void kernel_launch(void* const* d_in, const int* in_sizes, int n_in,
                              void* d_out, int out_size, void* d_ws, size_t ws_size,
                              hipStream_t stream) {
    const float4* boxes  = (const float4*)d_in[0];
    const float4* deltas = (const float4*)d_in[1];
    const float*  scores = (const float*)d_in[2];
    int n = in_sizes[2];                        // 10000
    int words  = (n + 63) >> 6;                 // 157
    int stride = (words + 3) & ~3;              // 160 (u64 words per row)
    int npad   = ((n + M_COLS - 1) / M_COLS) * M_COLS;  // 10240

    char* ws = (char*)d_ws;
    float4* refined = (float4*)ws;                                  // npad*16
    float4* sboxes  = (float4*)(ws + (size_t)npad * 16);            // npad*16
    int*    origIdx = (int*)(ws + (size_t)npad * 32);               // n*4
    size_t  moff    = ((size_t)npad * 32 + (size_t)n * 4 + 1023) & ~(size_t)1023;
    u64*    mask    = (u64*)(ws + moff);                            // n*stride*8

    float* out = (float*)d_out;

    k_refine<<<(npad + 255) / 256, 256, 0, stream>>>(
        boxes, deltas, (float4*)out, refined, sboxes, n, npad);
    k_rank<<<(n + 63) / 64, 256, 0, stream>>>(scores, refined, sboxes, origIdx, n);
    dim3 mgrid(npad / M_COLS, (n + M_RCHUNK - 1) / M_RCHUNK);
    k_mask<<<mgrid, 256, 0, stream>>>(sboxes, mask, n, npad, words, stride);
    k_scan<<<1, 256, 0, stream>>>(mask, origIdx, out + (size_t)n * 4, n, words, stride);
}